// Round 3
// baseline (37.046 us; speedup 1.0000x reference)
//
#include <hip/hip_runtime.h>

#define HH 256
#define WW 256
#define CC 8
#define TY 32
#define LW (WW + 2)          // padded LDS row: col 0 and 257 are zero
#define NSTRIP (HH / TY)     // 8 strips per image

// One block = one TY-row full-width strip of one image. One thread per column.
// Sliding 4-row ring of NORMALIZED affinity channels in LDS; raw next-row
// values prefetched into registers each iteration; rsum carried in registers.
// out(j,x) = cur(j,x) * [ a0(j+1,x+1)+a1(j+1,x)+a2(j+1,x-1)
//                        +a3(j,  x+1)          +a4(j,  x-1)
//                        +a5(j-1,x+1)+a6(j-1,x)+a7(j-1,x-1) ]
//          + coa(j,x) * (1 - rawsum(j,x)),   a_c = aff_c / sum_c|aff_c|
__global__ __launch_bounds__(256) void cspn_strip(
    const float* __restrict__ aff,   // [B, 8, H, W]
    const float* __restrict__ cur,   // [B, 1, H, W]
    const float* __restrict__ coa,   // [B, 1, H, W]
    float* __restrict__ out)         // [B, 1, H, W]
{
    __shared__ float ring[4][CC][LW];

    // bijective XCD swizzle: 512 blocks % 8 == 0 -> 64 consecutive wg per XCD
    // (all 8 strips of an image land on one XCD: boundary rows can hit L2)
    const int cpx = gridDim.x >> 3;
    int wg = blockIdx.x;
    wg = (wg & 7) * cpx + (wg >> 3);

    const int b  = wg >> 3;                    // image (NSTRIP == 8)
    const int y0 = (wg & (NSTRIP - 1)) * TY;   // strip start row
    const int x  = threadIdx.x;                // column 0..255

    // zero the x-pad columns once (4 slots x 8 ch x 2 sides = 64 entries)
    if (threadIdx.x < 64) {
        const int s = threadIdx.x >> 4;
        const int c = (threadIdx.x >> 1) & 7;
        ring[s][c][(threadIdx.x & 1) ? (LW - 1) : 0] = 0.f;
    }

    const size_t plane = (size_t)HH * WW;
    const float* __restrict__ ab = aff + (size_t)b * CC * plane;
    const size_t img = (size_t)b * plane;

    // prime: raw row y0-1 (zeros outside image)
    float r[CC];
    {
        const int yy = y0 - 1;
        const bool inb = ((unsigned)yy < HH);
        #pragma unroll
        for (int c = 0; c < CC; ++c)
            r[c] = inb ? ab[c * plane + (size_t)yy * WW + x] : 0.f;
    }
    float rsum_prev = 0.f;

    __syncthreads();

    for (int y = y0 - 1; y <= y0 + TY; ++y) {
        // ---- prefetch raw row y+1 into registers (hides HBM latency) ----
        float n[CC];
        const int yn = y + 1;
        const bool ldn = (yn <= y0 + TY) && ((unsigned)yn < HH);
        #pragma unroll
        for (int c = 0; c < CC; ++c)
            n[c] = ldn ? ab[c * plane + (size_t)yn * WW + x] : 0.f;

        const int j = y - 1;                 // output row finalized this iter
        const bool emit = (j >= y0);         // j < y0+TY always true here
        float cj = 0.f, oj = 0.f;
        if (emit) {
            cj = cur[img + (size_t)j * WW + x];
            oj = coa[img + (size_t)j * WW + x];
        }

        // ---- normalize row y -> ring slot ----
        float s = 0.f, rs = 0.f;
        #pragma unroll
        for (int c = 0; c < CC; ++c) { s += fabsf(r[c]); rs += r[c]; }
        const float invs = (s > 0.f) ? (1.0f / s) : 0.f;  // 0 for off-image rows
        const int slot = (y + 4) & 3;
        #pragma unroll
        for (int c = 0; c < CC; ++c) ring[slot][c][x + 1] = r[c] * invs;

        __syncthreads();

        // ---- gather output row j (needs rows j-1, j, j+1 in ring) ----
        if (emit) {
            const int sp = (y + 4) & 3;      // row j+1 == y
            const int sc = (y + 3) & 3;      // row j
            const int sm = (y + 2) & 3;      // row j-1
            const int xc = x + 1;
            const float sum =
                ring[sp][0][xc + 1] + ring[sp][1][xc] + ring[sp][2][xc - 1] +
                ring[sc][3][xc + 1]                   + ring[sc][4][xc - 1] +
                ring[sm][5][xc + 1] + ring[sm][6][xc] + ring[sm][7][xc - 1];
            out[img + (size_t)j * WW + x] = cj * sum + oj * (1.0f - rsum_prev);
        }

        rsum_prev = rs;                      // rs of row y -> used when j == y
        #pragma unroll
        for (int c = 0; c < CC; ++c) r[c] = n[c];
    }
}

extern "C" void kernel_launch(void* const* d_in, const int* in_sizes, int n_in,
                              void* d_out, int out_size, void* d_ws, size_t ws_size,
                              hipStream_t stream) {
    const float* aff = (const float*)d_in[0];   // [64, 8, 256, 256]
    const float* cur = (const float*)d_in[1];   // [64, 1, 256, 256]
    const float* coa = (const float*)d_in[2];   // [64, 1, 256, 256]
    float* out = (float*)d_out;                 // [64, 1, 256, 256]

    dim3 grid(64 * NSTRIP);                     // 512 blocks = 2 per CU, all resident
    dim3 block(256);
    cspn_strip<<<grid, block, 0, stream>>>(aff, cur, coa, out);
}

// Round 4
// 33.735 us; speedup vs baseline: 1.0982x; 1.0982x over previous
//
#include <hip/hip_runtime.h>

#define HH 256
#define WW 256
#define CC 8
#define TY 32                // strip rows; 512-thread block, 2 rows/iteration
#define LW (WW + 2)          // padded LDS row: col 0 and 257 are zero
#define NSTRIP (HH / TY)     // 8 strips per image

// One block = one 32-row full-width strip. 512 threads = 2 row-groups x 256 cols.
// 6-slot ring of normalized channels + rsum; one barrier per 2 rows.
// out(j,x) = cur(j,x) * [ a0(j+1,x+1)+a1(j+1,x)+a2(j+1,x-1)
//                        +a3(j,  x+1)          +a4(j,  x-1)
//                        +a5(j-1,x+1)+a6(j-1,x)+a7(j-1,x-1) ]
//          + coa(j,x) * (1 - rawsum(j,x)),   a_c = aff_c / sum_c|aff_c|
__global__ __launch_bounds__(512, 4) void cspn_pair(
    const float* __restrict__ aff,   // [B, 8, H, W]
    const float* __restrict__ cur,   // [B, 1, H, W]
    const float* __restrict__ coa,   // [B, 1, H, W]
    float* __restrict__ out)         // [B, 1, H, W]
{
    __shared__ float ring[6][CC][LW];   // normalized affinity, 6-row ring
    __shared__ float rsring[6][WW];     // raw channel-sum ring (crosses g-groups)

    // bijective XCD swizzle: 512 blocks % 8 == 0 -> 64 consecutive wg per XCD
    const int cpx = gridDim.x >> 3;
    int wg = blockIdx.x;
    wg = (wg & 7) * cpx + (wg >> 3);

    const int b  = wg >> 3;                    // image (NSTRIP == 8)
    const int y0 = (wg & (NSTRIP - 1)) * TY;   // strip start row
    const int x  = threadIdx.x & 255;          // column 0..255
    const int g  = threadIdx.x >> 8;           // row group 0/1

    // zero the x-pad columns once: 6 slots x 8 ch x 2 sides = 96 entries
    if (threadIdx.x < 96) {
        const int s = threadIdx.x >> 4;        // 0..5
        const int r = threadIdx.x & 15;
        ring[s][r >> 1][(r & 1) ? (LW - 1) : 0] = 0.f;
    }

    const size_t plane = (size_t)HH * WW;
    const float* __restrict__ ab = aff + (size_t)b * CC * plane;
    const size_t img = (size_t)b * plane;

    // prime: raw row y0-1+g (zeros outside image)
    float r_[CC];
    {
        const int yy = y0 - 1 + g;
        const bool inb = ((unsigned)yy < HH);
        #pragma unroll
        for (int c = 0; c < CC; ++c)
            r_[c] = inb ? ab[c * plane + (size_t)yy * WW + x] : 0.f;
    }
    __syncthreads();   // pad zeros visible before any gather

    for (int i = 0; i <= TY / 2; ++i) {        // 17 iterations, 2 rows each
        const int ya   = y0 - 1 + 2 * i;
        const int yrow = ya + g;               // row this group normalizes

        // ---- prefetch raw rows yrow+2 (next iteration) ----
        float n_[CC];
        const int yn = yrow + 2;
        const bool ldn = (yn <= y0 + TY) && ((unsigned)yn < HH);
        #pragma unroll
        for (int c = 0; c < CC; ++c)
            n_[c] = ldn ? ab[c * plane + (size_t)yn * WW + x] : 0.f;

        // ---- output row this group emits: j = ya-1+g ----
        const int j = ya - 1 + g;
        const bool emit = (j >= y0);           // j <= y0+TY-1 automatic
        float cj = 0.f, oj = 0.f;
        if (emit) {
            cj = cur[img + (size_t)j * WW + x];
            oj = coa[img + (size_t)j * WW + x];
        }

        // ---- normalize row yrow -> ring slot (yrow mod 6) ----
        float s = 0.f, rs = 0.f;
        #pragma unroll
        for (int c = 0; c < CC; ++c) { s += fabsf(r_[c]); rs += r_[c]; }
        const float invs = (s > 0.f) ? (1.0f / s) : 0.f;  // 0 off-image
        const int slot = (yrow + 12) % 6;
        #pragma unroll
        for (int c = 0; c < CC; ++c) ring[slot][c][x + 1] = r_[c] * invs;
        rsring[slot][x] = rs;

        __syncthreads();   // one barrier per 2 rows (6-slot ring makes it safe)

        // ---- gather output row j (rows j-1, j, j+1 all in ring) ----
        if (emit) {
            const int sp = slot;                         // row j+1 == yrow
            int sc = slot - 1; if (sc < 0) sc += 6;      // row j
            int sm = slot - 2; if (sm < 0) sm += 6;      // row j-1
            const int xc = x + 1;
            const float sum =
                ring[sp][0][xc + 1] + ring[sp][1][xc] + ring[sp][2][xc - 1] +
                ring[sc][3][xc + 1]                   + ring[sc][4][xc - 1] +
                ring[sm][5][xc + 1] + ring[sm][6][xc] + ring[sm][7][xc - 1];
            const float rsj = rsring[sc][x];
            out[img + (size_t)j * WW + x] = cj * sum + oj * (1.0f - rsj);
        }

        #pragma unroll
        for (int c = 0; c < CC; ++c) r_[c] = n_[c];
    }
}

extern "C" void kernel_launch(void* const* d_in, const int* in_sizes, int n_in,
                              void* d_out, int out_size, void* d_ws, size_t ws_size,
                              hipStream_t stream) {
    const float* aff = (const float*)d_in[0];   // [64, 8, 256, 256]
    const float* cur = (const float*)d_in[1];   // [64, 1, 256, 256]
    const float* coa = (const float*)d_in[2];   // [64, 1, 256, 256]
    float* out = (float*)d_out;                 // [64, 1, 256, 256]

    dim3 grid(64 * NSTRIP);                     // 512 blocks = 2 per CU, 16 waves/CU
    dim3 block(512);
    cspn_pair<<<grid, block, 0, stream>>>(aff, cur, coa, out);
}